// Round 3
// baseline (169.404 us; speedup 1.0000x reference)
//
#include <hip/hip_runtime.h>
#include <hip/hip_fp16.h>

// SuppLayer: out[b,c] = exp( sum_s x[b, cm[c,s]] * w[c,s] )
// B=4096, NCLASS=1000, NSUPP=64, NCHUNK=4096.
//
// Block = 1024 threads, BT=8 batch rows, 64 KB LDS tile of x rows stored
// TRANSPOSED as fp16 (slot idx = 16 B = 8 rows' values at column idx);
// one ds_read_b128 per (class,s) feeds 8 fp32 FMAs.
//
// R2 fix: one-class-per-thread made cm/w loads 256B-lane-stride scattered
// (64 cache lines per wave instruction -> ~27us of VMEM serialization).
// Pre-pass transposes cm/w into d_ws as [sg][class] so gather loads are
// fully coalesced (16B lane stride).

constexpr int B_       = 4096;
constexpr int NCLASS_  = 1000;
constexpr int NSUPP_   = 64;
constexpr int NCHUNK_  = 4096;
constexpr int BT       = 8;      // batch rows per block
constexpr int THREADS_ = 1024;
constexpr int SG_      = NSUPP_ / 4;            // 16 int4/float4 groups
constexpr size_t CMT_BYTES = (size_t)SG_ * NCLASS_ * 16;   // 256 KB
constexpr size_t WS_NEEDED = 2 * CMT_BYTES;                // 512 KB

// ---- pre-pass: cm,w (class-major) -> [sg][class] int4/float4 in ws ----
__global__ void transpose_cw_kernel(const int*   __restrict__ cm,
                                    const float* __restrict__ w,
                                    int4*        __restrict__ cmT,
                                    float4*      __restrict__ wT)
{
    const int tid = blockIdx.x * 256 + threadIdx.x;   // 0..31999
    if (tid < SG_ * NCLASS_) {
        const int sg = tid / NCLASS_, c = tid % NCLASS_;
        cmT[tid] = reinterpret_cast<const int4*>(cm)[c * SG_ + sg];
    } else if (tid < 2 * SG_ * NCLASS_) {
        const int k = tid - SG_ * NCLASS_;
        const int sg = k / NCLASS_, c = k % NCLASS_;
        wT[k] = reinterpret_cast<const float4*>(w)[c * SG_ + sg];
    }
}

__global__ __launch_bounds__(THREADS_, 8)
void supp_gather_kernel(const float* __restrict__ x,
                        const float* __restrict__ wSupp,
                        const int*   __restrict__ cmap,
                        const float4* __restrict__ wT,
                        const int4*   __restrict__ cmT,
                        int           useT,
                        float*       __restrict__ out)
{
    // tile[c*4 + k] = half2(row 2k, row 2k+1) at column c   (64 KB)
    __shared__ __align__(16) __half2 tile[NCHUNK_ * (BT / 2)];

    const int t  = threadIdx.x;
    const int rb = blockIdx.x * BT;   // first batch row of this tile

    // ---- stage: 8 rows of x -> fp16, transposed into LDS ----
    // thread t owns columns c = t + 1024p. Global: 4B coalesced.
    // LDS write: float4 at byte addr c*16 -> 16B lane stride, conflict-free.
    #pragma unroll
    for (int p = 0; p < NCHUNK_ / THREADS_; ++p) {   // 4 iterations
        const int c = t + THREADS_ * p;
        float v[BT];
        #pragma unroll
        for (int bi = 0; bi < BT; ++bi)
            v[bi] = x[(size_t)(rb + bi) * NCHUNK_ + c];
        __half2 h[BT / 2];
        #pragma unroll
        for (int k = 0; k < BT / 2; ++k)
            h[k] = __floats2half2_rn(v[2 * k], v[2 * k + 1]);
        *reinterpret_cast<float4*>(&tile[(size_t)c * 4]) =
            *reinterpret_cast<float4*>(h);
    }
    __syncthreads();

    // ---- gather: one class per thread, coalesced cm/w via transposed ws ----
    if (t < NCLASS_) {
        const int c = t;
        const int4*   cm4 = reinterpret_cast<const int4*>(cmap  + c * NSUPP_);
        const float4* w4  = reinterpret_cast<const float4*>(wSupp + c * NSUPP_);
        float acc[BT] = {0.f, 0.f, 0.f, 0.f, 0.f, 0.f, 0.f, 0.f};
        #pragma unroll 4
        for (int sg = 0; sg < SG_; ++sg) {
            int4   ci;
            float4 wf;
            if (useT) {                       // wave-uniform branch
                ci = cmT[sg * NCLASS_ + c];   // 16B lane stride: coalesced
                wf = wT [sg * NCLASS_ + c];
            } else {
                ci = cm4[sg];
                wf = w4[sg];
            }
            const int   idx[4] = {ci.x, ci.y, ci.z, ci.w};
            const float wv[4]  = {wf.x, wf.y, wf.z, wf.w};
            #pragma unroll
            for (int j = 0; j < 4; ++j) {
                union { float4 f4; __half2 h2[4]; } u;
                u.f4 = *reinterpret_cast<const float4*>(
                           &tile[(size_t)idx[j] * 4]);     // ds_read_b128
                #pragma unroll
                for (int k = 0; k < 4; ++k) {
                    const float2 f = __half22float2(u.h2[k]);
                    acc[2 * k]     = fmaf(f.x, wv[j], acc[2 * k]);
                    acc[2 * k + 1] = fmaf(f.y, wv[j], acc[2 * k + 1]);
                }
            }
        }
        #pragma unroll
        for (int bi = 0; bi < BT; ++bi)
            out[(size_t)(rb + bi) * NCLASS_ + c] = __expf(acc[bi]);
    }
}

extern "C" void kernel_launch(void* const* d_in, const int* in_sizes, int n_in,
                              void* d_out, int out_size, void* d_ws, size_t ws_size,
                              hipStream_t stream) {
    const float* x  = (const float*)d_in[0];   // (B, NCHUNK) fp32
    const float* w  = (const float*)d_in[1];   // (NCLASS, NSUPP) fp32
    const int*   cm = (const int*)d_in[2];     // (NCLASS, NSUPP) int32
    float*       o  = (float*)d_out;           // (B, NCLASS) fp32

    const int useT = (ws_size >= WS_NEEDED) ? 1 : 0;
    int4*   cmT = (int4*)d_ws;
    float4* wT  = (float4*)((char*)d_ws + CMT_BYTES);

    if (useT) {
        const int total = 2 * SG_ * NCLASS_;             // 32000 threads
        transpose_cw_kernel<<<dim3((total + 255) / 256), dim3(256), 0, stream>>>(
            cm, w, cmT, wT);
    }
    supp_gather_kernel<<<dim3(B_ / BT), dim3(THREADS_), 0, stream>>>(
        x, w, cm, wT, cmT, useT, o);
}

// Round 4
// 115.386 us; speedup vs baseline: 1.4682x; 1.4682x over previous
//
#include <hip/hip_runtime.h>
#include <hip/hip_fp16.h>

// SuppLayer: out[b,c] = exp( sum_s x[b, cm[c,s]] * w[c,s] )
// B=4096, NCLASS=1000, NSUPP=64, NCHUNK=4096.
//
// Block = 1024 threads, BT=8 batch rows, 64 KB LDS tile of x rows stored
// TRANSPOSED as fp16 (slot idx = 16 B = 8 rows' values at column idx);
// one ds_read_b128 per (class,s) feeds 8 fp32 FMAs. One class per thread.
//
// cm/w are pre-transposed into d_ws as [sg][class] so gather-phase loads
// are coalesced (16 B lane stride).
// R3 lesson: the useT selection MUST be compile-time — a dynamic branch in
// the unrolled hot loop caused scratch spill (+200 MB HBM traffic, 86 us).

constexpr int B_       = 4096;
constexpr int NCLASS_  = 1000;
constexpr int NSUPP_   = 64;
constexpr int NCHUNK_  = 4096;
constexpr int BT       = 8;      // batch rows per block
constexpr int THREADS_ = 1024;
constexpr int SG_      = NSUPP_ / 4;            // 16 int4/float4 groups
constexpr size_t CMT_BYTES = (size_t)SG_ * NCLASS_ * 16;   // 256 KB
constexpr size_t WS_NEEDED = 2 * CMT_BYTES;                // 512 KB

// ---- pre-pass: cm,w (class-major) -> [sg][class] int4/float4 in ws ----
__global__ void transpose_cw_kernel(const int*   __restrict__ cm,
                                    const float* __restrict__ w,
                                    int4*        __restrict__ cmT,
                                    float4*      __restrict__ wT)
{
    const int tid = blockIdx.x * 256 + threadIdx.x;   // 0..31999
    if (tid < SG_ * NCLASS_) {
        const int sg = tid / NCLASS_, c = tid % NCLASS_;
        cmT[tid] = reinterpret_cast<const int4*>(cm)[c * SG_ + sg];
    } else if (tid < 2 * SG_ * NCLASS_) {
        const int k = tid - SG_ * NCLASS_;
        const int sg = k / NCLASS_, c = k % NCLASS_;
        wT[k] = reinterpret_cast<const float4*>(w)[c * SG_ + sg];
    }
}

template <bool USET>
__global__ __launch_bounds__(THREADS_, 8)
void supp_gather_kernel(const float* __restrict__ x,
                        const float* __restrict__ wSupp,
                        const int*   __restrict__ cmap,
                        const float4* __restrict__ wT,
                        const int4*   __restrict__ cmT,
                        float*       __restrict__ out)
{
    // tile[c*4 + k] = half2(row 2k, row 2k+1) at column c   (64 KB)
    __shared__ __align__(16) __half2 tile[NCHUNK_ * (BT / 2)];

    const int t  = threadIdx.x;
    const int rb = blockIdx.x * BT;   // first batch row of this tile

    // ---- stage: 8 rows of x -> fp16, transposed into LDS ----
    // thread t owns columns c = t + 1024p. Global: 4B coalesced.
    // LDS write: float4 at byte addr c*16 -> 16B lane stride, conflict-free.
    #pragma unroll
    for (int p = 0; p < NCHUNK_ / THREADS_; ++p) {   // 4 iterations
        const int c = t + THREADS_ * p;
        float v[BT];
        #pragma unroll
        for (int bi = 0; bi < BT; ++bi)
            v[bi] = x[(size_t)(rb + bi) * NCHUNK_ + c];
        __half2 h[BT / 2];
        #pragma unroll
        for (int k = 0; k < BT / 2; ++k)
            h[k] = __floats2half2_rn(v[2 * k], v[2 * k + 1]);
        *reinterpret_cast<float4*>(&tile[(size_t)c * 4]) =
            *reinterpret_cast<float4*>(h);
    }
    __syncthreads();

    // ---- gather: one class per thread ----
    if (t < NCLASS_) {
        const int c = t;
        float acc[BT] = {0.f, 0.f, 0.f, 0.f, 0.f, 0.f, 0.f, 0.f};
        #pragma unroll 4
        for (int sg = 0; sg < SG_; ++sg) {
            int4   ci;
            float4 wf;
            if constexpr (USET) {
                ci = cmT[sg * NCLASS_ + c];   // 16B lane stride: coalesced
                wf = wT [sg * NCLASS_ + c];
            } else {
                ci = reinterpret_cast<const int4*>(cmap + c * NSUPP_)[sg];
                wf = reinterpret_cast<const float4*>(wSupp + c * NSUPP_)[sg];
            }
            const int   idx[4] = {ci.x, ci.y, ci.z, ci.w};
            const float wv[4]  = {wf.x, wf.y, wf.z, wf.w};
            #pragma unroll
            for (int j = 0; j < 4; ++j) {
                union { float4 f4; __half2 h2[4]; } u;
                u.f4 = *reinterpret_cast<const float4*>(
                           &tile[(size_t)idx[j] * 4]);     // ds_read_b128
                #pragma unroll
                for (int k = 0; k < 4; ++k) {
                    const float2 f = __half22float2(u.h2[k]);
                    acc[2 * k]     = fmaf(f.x, wv[j], acc[2 * k]);
                    acc[2 * k + 1] = fmaf(f.y, wv[j], acc[2 * k + 1]);
                }
            }
        }
        #pragma unroll
        for (int bi = 0; bi < BT; ++bi)
            out[(size_t)(rb + bi) * NCLASS_ + c] = __expf(acc[bi]);
    }
}

extern "C" void kernel_launch(void* const* d_in, const int* in_sizes, int n_in,
                              void* d_out, int out_size, void* d_ws, size_t ws_size,
                              hipStream_t stream) {
    const float* x  = (const float*)d_in[0];   // (B, NCHUNK) fp32
    const float* w  = (const float*)d_in[1];   // (NCLASS, NSUPP) fp32
    const int*   cm = (const int*)d_in[2];     // (NCLASS, NSUPP) int32
    float*       o  = (float*)d_out;           // (B, NCLASS) fp32

    int4*   cmT = (int4*)d_ws;
    float4* wT  = (float4*)((char*)d_ws + CMT_BYTES);

    if (ws_size >= WS_NEEDED) {
        const int total = 2 * SG_ * NCLASS_;             // 32000 threads
        transpose_cw_kernel<<<dim3((total + 255) / 256), dim3(256), 0, stream>>>(
            cm, w, cmT, wT);
        supp_gather_kernel<true><<<dim3(B_ / BT), dim3(THREADS_), 0, stream>>>(
            x, w, cm, wT, cmT, o);
    } else {
        supp_gather_kernel<false><<<dim3(B_ / BT), dim3(THREADS_), 0, stream>>>(
            x, w, cm, wT, cmT, o);
    }
}